// Round 9
// baseline (214.593 us; speedup 1.0000x reference)
//
#include <hip/hip_runtime.h>
#include <hip/hip_bf16.h>
#include <cstdint>
#include <cstddef>

typedef __bf16 bf16;
typedef __bf16 bf16x4 __attribute__((ext_vector_type(4)));
typedef __bf16 bf16x8 __attribute__((ext_vector_type(8)));
typedef float f32x4 __attribute__((ext_vector_type(4)));
typedef float f32x16 __attribute__((ext_vector_type(16)));

#define MFMA16(a, b, c) __builtin_amdgcn_mfma_f32_16x16x32_bf16((a), (b), (c), 0, 0, 0)
#define MFMA32(a, b, c) __builtin_amdgcn_mfma_f32_32x32x16_bf16((a), (b), (c), 0, 0, 0)
#define GLD16(g, l) __builtin_amdgcn_global_load_lds( \
    (const __attribute__((address_space(1))) void*)(g), \
    (__attribute__((address_space(3))) void*)(l), 16, 0, 0)

constexpr int Bsz = 4, SX = 2048, SC = 2048, Dm = 512, H = 8, DK = 64;
constexpr float L2E = 1.4426950408889634f;

// ---------------------------------------------------------------------------
// cvt_all: one kernel for all conversions (block-range dispatch).
// ---------------------------------------------------------------------------
__global__ __launch_bounds__(256) void cvt_all(
    const float* __restrict__ x, const float* __restrict__ c,
    const float* __restrict__ Wq, const float* __restrict__ Wk,
    const float* __restrict__ Wv, const float* __restrict__ Wo,
    const float* __restrict__ rel,
    bf16* __restrict__ xcOut, bf16* __restrict__ wOut, float* __restrict__ relT)
{
    int blk = blockIdx.x;
    if (blk < 4096) {
        int i = (blk * 256 + threadIdx.x) * 8;
        const float* src = (i < 4194304) ? x : c;
        int off = i & 4194303;
        float4 v0 = *(const float4*)(src + off);
        float4 v1 = *(const float4*)(src + off + 4);
        bf16x8 o = { (bf16)v0.x, (bf16)v0.y, (bf16)v0.z, (bf16)v0.w,
                     (bf16)v1.x, (bf16)v1.y, (bf16)v1.z, (bf16)v1.w };
        *(bf16x8*)(xcOut + i) = o;
    } else if (blk < 4608) {
        int i = ((blk - 4096) * 256 + threadIdx.x) * 8;
        int w = i >> 18;
        int off = i & 262143;
        const float* src = (w == 0) ? Wq : (w == 1) ? Wk : (w == 2) ? Wv : Wo;
        float4 v0 = *(const float4*)(src + off);
        float4 v1 = *(const float4*)(src + off + 4);
        bf16x8 o = { (bf16)v0.x, (bf16)v0.y, (bf16)v0.z, (bf16)v0.w,
                     (bf16)v1.x, (bf16)v1.y, (bf16)v1.z, (bf16)v1.w };
        *(bf16x8*)(wOut + i) = o;
    } else {
        int q = blk - 4608;
        int h = q >> 4;
        int i = (q & 15) * 256 + threadIdx.x;
        if (i < SX + SC - 1) relT[h * (SX + SC - 1) + i] = rel[i * H + h] * L2E;
    }
}

// ---------------------------------------------------------------------------
// qkv_gemm v2: fused Q/K/V projections with single-barrier LDS double-buffer.
// grid (12, 64) = 768 blocks. Tile 128x128, BK=64, 256 thr = 4 waves,
// wave tile 64x64 (4x4 MFMA16). Loop: barrier -> issue stage(k+1) to buf^1 ->
// compute buf  (prefetch retires during the compute phase, so the next
// barrier's vmcnt(0) drain is cheap). LDS 64 KB -> 2 blocks/CU.
// ---------------------------------------------------------------------------
__global__ __launch_bounds__(256, 2) void qkv_gemm(
    const bf16* __restrict__ Xbf, const bf16* __restrict__ Cbf,
    const bf16* __restrict__ Wbf,
    const float* __restrict__ bq, const float* __restrict__ bk,
    const float* __restrict__ bv,
    bf16* __restrict__ Qw, bf16* __restrict__ Kw, bf16* __restrict__ Vw)
{
    __shared__ alignas(16) bf16 As[2][128 * 64];
    __shared__ alignas(16) bf16 Bs[2][128 * 64];

    const int proj = blockIdx.x >> 2;
    const int n0 = (blockIdx.x & 3) * 128;
    const int m0 = blockIdx.y * 128;
    const bf16* A = (proj == 0) ? Xbf : Cbf;
    const bf16* W = Wbf + proj * 262144;
    const float* bias = (proj == 0) ? bq : (proj == 1) ? bk : bv;

    const int t = threadIdx.x;
    const int wid = t >> 6, lane = t & 63, lr = lane & 15, lq = lane >> 4;
    const int wm = (wid & 1) * 64, wn = (wid >> 1) * 64;

    const int rl = lane >> 3;             // 0..7 row within 8-row staging group
    const int ch = (lane & 7) ^ rl;       // xor-swizzled global 16B chunk

    const bf16* ga0 = A + (size_t)(m0 + wid * 32 + rl) * Dm + ch * 8;
    const bf16* gb0 = W + (size_t)(n0 + wid * 32 + rl) * Dm + ch * 8;

    f32x4 acc[4][4];
#pragma unroll
    for (int i = 0; i < 4; i++)
#pragma unroll
        for (int j = 0; j < 4; j++) acc[i][j] = f32x4{0.f, 0.f, 0.f, 0.f};

    // prologue: stage k=0 into buf 0
#pragma unroll
    for (int g = 0; g < 4; g++) {
        GLD16(ga0 + (size_t)g * 8 * Dm, &As[0][(wid * 32 + g * 8) * 64]);
        GLD16(gb0 + (size_t)g * 8 * Dm, &Bs[0][(wid * 32 + g * 8) * 64]);
    }

    for (int k = 0; k < 8; k++) {
        __syncthreads();                       // drains stage(k) (in flight a full phase)
        const int cur = k & 1;
        if (k < 7) {                           // issue prefetch of k+1 to other buffer
            const bf16* ga = ga0 + (k + 1) * 64;
            const bf16* gb = gb0 + (k + 1) * 64;
#pragma unroll
            for (int g = 0; g < 4; g++) {
                GLD16(ga + (size_t)g * 8 * Dm, &As[cur ^ 1][(wid * 32 + g * 8) * 64]);
                GLD16(gb + (size_t)g * 8 * Dm, &Bs[cur ^ 1][(wid * 32 + g * 8) * 64]);
            }
        }
#pragma unroll
        for (int ks = 0; ks < 2; ks++) {
            bf16x8 af[4], bfr[4];
#pragma unroll
            for (int mt = 0; mt < 4; mt++)
                af[mt] = *(const bf16x8*)&As[cur][(wm + mt * 16 + lr) * 64 + (((ks * 4 + lq) ^ (lr & 7)) * 8)];
#pragma unroll
            for (int nt = 0; nt < 4; nt++)
                bfr[nt] = *(const bf16x8*)&Bs[cur][(wn + nt * 16 + lr) * 64 + (((ks * 4 + lq) ^ (lr & 7)) * 8)];
#pragma unroll
            for (int mt = 0; mt < 4; mt++)
#pragma unroll
                for (int nt = 0; nt < 4; nt++)
                    acc[mt][nt] = MFMA16(af[mt], bfr[nt], acc[mt][nt]);
        }
    }

    // epilogue (wave-uniform proj branch; layouts proven R5-R8)
#pragma unroll
    for (int mt = 0; mt < 4; mt++) {
#pragma unroll
        for (int nt = 0; nt < 4; nt++) {
#pragma unroll
            for (int r = 0; r < 4; r++) {
                int m = m0 + wm + mt * 16 + lq * 4 + r;   // b*2048 + s
                int n = n0 + wn + nt * 16 + lr;           // h*64 + dk
                float v = acc[mt][nt][r] + bias[n];
                int bh = (m >> 11) * 8 + (n >> 6);
                int key = m & 2047, dk = n & 63;
                if (proj == 0) {
                    Qw[(size_t)(bh * 2048 + key) * 64 + dk] = (bf16)v;
                } else if (proj == 1) {
                    int idx = ((((bh * 64 + (key >> 5)) * 4 + (dk >> 4)) * 2 + ((dk >> 3) & 1)) * 32
                               + (key & 31)) * 8 + (dk & 7);
                    Kw[idx] = (bf16)v;
                } else {
                    int idx = (((((bh * 32 + (key >> 6)) * 4 + ((key >> 4) & 3)) * 2 + (dk >> 5)) * 2
                                + ((key >> 3) & 1)) * 32 + (dk & 31)) * 8 + (key & 7);
                    Vw[idx] = (bf16)v;
                }
            }
        }
    }
}

// ---------------------------------------------------------------------------
// out_gemm v2: Y = A @ Wo^T + bo, fp32 out. Tile 64(M) x 128(N), BK=64,
// grid (4, 128) = 512 blocks (2/CU), same single-barrier double-buffer.
// LDS 2*(8+16) = 48 KB.
// ---------------------------------------------------------------------------
__global__ __launch_bounds__(256, 2) void out_gemm(
    const bf16* __restrict__ A, const bf16* __restrict__ W,
    const float* __restrict__ bias, float* __restrict__ Y)
{
    __shared__ alignas(16) bf16 As[2][64 * 64];
    __shared__ alignas(16) bf16 Bs[2][128 * 64];

    const int t = threadIdx.x;
    const int n0 = blockIdx.x * 128;
    const int m0 = blockIdx.y * 64;
    const int wid = t >> 6, lane = t & 63, lr = lane & 15, lq = lane >> 4;
    const int wn = wid * 32;

    const int rl = lane >> 3;
    const int ch = (lane & 7) ^ rl;

    const bf16* ga0 = A + (size_t)(m0 + wid * 16 + rl) * Dm + ch * 8;
    const bf16* gb0 = W + (size_t)(n0 + wid * 32 + rl) * Dm + ch * 8;

    f32x4 acc[4][2];
#pragma unroll
    for (int i = 0; i < 4; i++)
#pragma unroll
        for (int j = 0; j < 2; j++) acc[i][j] = f32x4{0.f, 0.f, 0.f, 0.f};

#pragma unroll
    for (int g = 0; g < 2; g++)
        GLD16(ga0 + (size_t)g * 8 * Dm, &As[0][(wid * 16 + g * 8) * 64]);
#pragma unroll
    for (int g = 0; g < 4; g++)
        GLD16(gb0 + (size_t)g * 8 * Dm, &Bs[0][(wid * 32 + g * 8) * 64]);

    for (int k = 0; k < 8; k++) {
        __syncthreads();
        const int cur = k & 1;
        if (k < 7) {
            const bf16* ga = ga0 + (k + 1) * 64;
            const bf16* gb = gb0 + (k + 1) * 64;
#pragma unroll
            for (int g = 0; g < 2; g++)
                GLD16(ga + (size_t)g * 8 * Dm, &As[cur ^ 1][(wid * 16 + g * 8) * 64]);
#pragma unroll
            for (int g = 0; g < 4; g++)
                GLD16(gb + (size_t)g * 8 * Dm, &Bs[cur ^ 1][(wid * 32 + g * 8) * 64]);
        }
#pragma unroll
        for (int ks = 0; ks < 2; ks++) {
            bf16x8 af[4], bfr[2];
#pragma unroll
            for (int mt = 0; mt < 4; mt++)
                af[mt] = *(const bf16x8*)&As[cur][(mt * 16 + lr) * 64 + (((ks * 4 + lq) ^ (lr & 7)) * 8)];
#pragma unroll
            for (int nt = 0; nt < 2; nt++)
                bfr[nt] = *(const bf16x8*)&Bs[cur][(wn + nt * 16 + lr) * 64 + (((ks * 4 + lq) ^ (lr & 7)) * 8)];
#pragma unroll
            for (int mt = 0; mt < 4; mt++)
#pragma unroll
                for (int nt = 0; nt < 2; nt++)
                    acc[mt][nt] = MFMA16(af[mt], bfr[nt], acc[mt][nt]);
        }
    }

#pragma unroll
    for (int mt = 0; mt < 4; mt++) {
#pragma unroll
        for (int nt = 0; nt < 2; nt++) {
#pragma unroll
            for (int r = 0; r < 4; r++) {
                int m = m0 + mt * 16 + lq * 4 + r;
                int n = n0 + wn + nt * 16 + lr;
                Y[(size_t)m * Dm + n] = acc[mt][nt][r] + bias[n];
            }
        }
    }
}

// ---------------------------------------------------------------------------
// attn v9 = R7 (proven 70.4 µs: unroll 1, frag-major K/V, FETCH 12-17 MB)
// + V-loads hoisted to tile top: issued before the S phase, consumed ~400 cyc
// later in PV -> V latency fully hidden. Live regs ~96-122 < 128 cap.
// ---------------------------------------------------------------------------
constexpr int PST = 72;  // P row stride (bf16)

__global__ __launch_bounds__(128, 4) void attn_kernel(
    const bf16* __restrict__ Qm, const bf16* __restrict__ Kf,
    const bf16* __restrict__ Vf, const float* __restrict__ relT,
    bf16* __restrict__ Oa)
{
    const int id = blockIdx.x;
    const int xcd = id & 7, j = id >> 3;
    const int bh = xcd + 8 * (j & 3);
    const int q0 = (j >> 2) * 32;
    const int h = bh & 7, b = bh >> 3;
    const int t = threadIdx.x;
    const int wid = t >> 6, lane = t & 63;
    const int l31 = lane & 31, l5 = lane >> 5;

    __shared__ alignas(16) char sm[19456];
    bf16*  Ps   = (bf16*)(sm + wid * 4608);      // per-wave 32 x PST
    float* Osum = (float*)(sm + 9216);           // 64 lanes x 36 floats
    float* Bsl  = (float*)(sm + 18432) + wid * 96;
    float* Ls1  = (float*)(sm + 19200);
    float* Lfin = (float*)(sm + 19328);

    const bf16* Qb = Qm + (size_t)bh * SC * DK;
    const bf16* Kb = Kf + (size_t)bh * 64 * 2048;   // 64 key-grps x (4 ks x 512)
    const bf16* Vb = Vf + (size_t)bh * 32 * 4096;   // 32 tiles x (4 ks x 2 ng x 512)
    const float* rT = relT + h * (SX + SC - 1);

    // Q B-fragments (n=q, k=dk), resident all kernel
    bf16x8 qf[4];
#pragma unroll
    for (int ks = 0; ks < 4; ks++)
        qf[ks] = *(const bf16x8*)&Qb[(size_t)(q0 + l31) * DK + ks * 16 + l5 * 8];

    f32x16 oacc[2];
#pragma unroll
    for (int ng = 0; ng < 2; ng++)
#pragma unroll
        for (int r = 0; r < 16; r++) oacc[ng][r] = 0.f;
    float lsum = 0.f;

    const float sc = 0.125f * L2E;
    const int kw0 = wid << 10;       // wave's key base

#pragma unroll 1
    for (int tt = 0; tt < 16; ++tt) {
        const int k0 = kw0 + tt * 64;
        int i0 = q0 - k0 + 1984;
        Bsl[lane] = rT[i0 + lane];
        if (lane < 31) Bsl[64 + lane] = rT[i0 + 64 + lane];

        // ---- hoisted V loads: issue now, consume in PV (latency hidden) ----
        const bf16* vb = Vb + (size_t)(k0 >> 6) * 4096 + lane * 8;
        bf16x8 vf[8];
#pragma unroll
        for (int ng = 0; ng < 2; ng++)
#pragma unroll
            for (int ks = 0; ks < 4; ks++)
                vf[ng * 4 + ks] = *(const bf16x8*)(vb + ng * 512 + ks * 1024);

        // ---- S^T = K·Q^T per 32-key group; exp2; P->LDS ----
#pragma unroll
        for (int kg = 0; kg < 2; kg++) {
            const bf16* kb = Kb + (size_t)((k0 >> 5) + kg) * 2048 + lane * 8;
            f32x16 s;
#pragma unroll
            for (int r = 0; r < 16; r++) s[r] = 0.f;
#pragma unroll
            for (int ks = 0; ks < 4; ks++) {
                bf16x8 kf = *(const bf16x8*)(kb + ks * 512);   // contiguous 1KB wave-load
                s = MFMA32(kf, qf[ks], s);  // D[key][q], lane col = q
            }
#pragma unroll
            for (int r4 = 0; r4 < 4; r4++) {
                float p[4];
#pragma unroll
                for (int r0 = 0; r0 < 4; r0++) {
                    int n = r0 + 8 * r4 + 4 * l5;            // key_local in group
                    int ib = 63 + l31 - (kg * 32 + n);
                    p[r0] = __builtin_amdgcn_exp2f(s[r4 * 4 + r0] * sc + Bsl[ib]);
                    lsum += p[r0];
                }
                bf16x4 pk = { (bf16)p[0], (bf16)p[1], (bf16)p[2], (bf16)p[3] };
                *(bf16x4*)&Ps[l31 * PST + kg * 32 + 8 * r4 + 4 * l5] = pk;
            }
        }
        // ---- O += P @ V  (same-wave LDS RAW; no barrier) ----
        bf16x8 pf[4];
#pragma unroll
        for (int ks = 0; ks < 4; ks++)
            pf[ks] = *(const bf16x8*)&Ps[l31 * PST + ks * 16 + l5 * 8];
#pragma unroll
        for (int ng = 0; ng < 2; ng++)
#pragma unroll
            for (int ks = 0; ks < 4; ks++)
                oacc[ng] = MFMA32(pf[ks], vf[ng * 4 + ks], oacc[ng]);  // D[q][dk]
    }

    // ---- 2-way combine ----
    lsum += __shfl_xor(lsum, 32, 64);
    if (wid == 1) {
        if (lane < 32) Ls1[l31] = lsum;
        float* Op = Osum + lane * 36;
#pragma unroll
        for (int ng = 0; ng < 2; ng++)
#pragma unroll
            for (int q = 0; q < 4; q++) {
                f32x4 v = { oacc[ng][q * 4 + 0], oacc[ng][q * 4 + 1],
                            oacc[ng][q * 4 + 2], oacc[ng][q * 4 + 3] };
                *(f32x4*)(Op + ng * 16 + q * 4) = v;
            }
    }
    __syncthreads();
    if (wid == 0) {
        lsum += Ls1[l31];
        const float* Op = Osum + lane * 36;
#pragma unroll
        for (int ng = 0; ng < 2; ng++)
#pragma unroll
            for (int q = 0; q < 4; q++) {
                f32x4 v = *(const f32x4*)(Op + ng * 16 + q * 4);
#pragma unroll
                for (int r0 = 0; r0 < 4; r0++) oacc[ng][q * 4 + r0] += v[r0];
            }
        if (lane < 32) Lfin[l31] = lsum;
        // epilogue: normalize, store bf16 [b][q][h*64+dk]
#pragma unroll
        for (int r4 = 0; r4 < 4; r4++) {
            float4 lv = *(const float4*)&Lfin[8 * r4 + 4 * l5];
            float rv[4] = { 1.f / lv.x, 1.f / lv.y, 1.f / lv.z, 1.f / lv.w };
#pragma unroll
            for (int ng = 0; ng < 2; ng++) {
#pragma unroll
                for (int r0 = 0; r0 < 4; r0++) {
                    int row = r0 + 8 * r4 + 4 * l5;
                    Oa[((size_t)(b * SX + q0 + row)) * Dm + h * 64 + ng * 32 + l31] =
                        (bf16)(oacc[ng][r4 * 4 + r0] * rv[r0]);
                }
            }
        }
    }
}

// ---------------------------------------------------------------------------
// Launch
// ---------------------------------------------------------------------------
extern "C" void kernel_launch(void* const* d_in, const int* in_sizes, int n_in,
                              void* d_out, int out_size, void* d_ws, size_t ws_size,
                              hipStream_t stream)
{
    (void)in_sizes; (void)n_in; (void)out_size; (void)ws_size;

    const float* x   = (const float*)d_in[0];
    const float* c   = (const float*)d_in[1];
    const float* Wq  = (const float*)d_in[2];
    const float* bq  = (const float*)d_in[3];
    const float* Wk  = (const float*)d_in[4];
    const float* bk  = (const float*)d_in[5];
    const float* Wv  = (const float*)d_in[6];
    const float* bv  = (const float*)d_in[7];
    const float* Wo  = (const float*)d_in[8];
    const float* bo  = (const float*)d_in[9];
    const float* rel = (const float*)d_in[10];

    char* ws = (char*)d_ws;
    // layout: Wbf 0..2MB | XCbf 2..18MB (dead after QKV) / Aw overlay 2..10MB
    //         Q 18..26 | Kf 26..34 | Vf 34..42 | relT 42MB+128KB
    bf16*  Wbf  = (bf16*)ws;
    bf16*  Xbf  = (bf16*)(ws + (2u << 20));
    bf16*  Cbf  = Xbf + 4194304;
    bf16*  Aw   = (bf16*)(ws + (2u << 20));      // overlays XCbf (dead by then)
    bf16*  Qw   = (bf16*)(ws + (18u << 20));
    bf16*  Kw   = (bf16*)(ws + (26u << 20));
    bf16*  Vw   = (bf16*)(ws + (34u << 20));
    float* relT = (float*)(ws + (42u << 20));

    cvt_all<<<4736, 256, 0, stream>>>(x, c, Wq, Wk, Wv, Wo, rel, Xbf, Wbf, relT);

    qkv_gemm<<<dim3(12, 64), 256, 0, stream>>>(Xbf, Cbf, Wbf, bq, bk, bv, Qw, Kw, Vw);

    attn_kernel<<<2048, 128, 0, stream>>>(Qw, Kw, Vw, relT, Aw);

    out_gemm<<<dim3(4, 128), 256, 0, stream>>>(Aw, Wbf + 3 * 262144, bo, (float*)d_out);
}

// Round 10
// 189.821 us; speedup vs baseline: 1.1305x; 1.1305x over previous
//
#include <hip/hip_runtime.h>
#include <hip/hip_bf16.h>
#include <cstdint>
#include <cstddef>

typedef __bf16 bf16;
typedef __bf16 bf16x4 __attribute__((ext_vector_type(4)));
typedef __bf16 bf16x8 __attribute__((ext_vector_type(8)));
typedef float f32x4 __attribute__((ext_vector_type(4)));
typedef float f32x4u __attribute__((ext_vector_type(4), aligned(4)));  // 4B-aligned vec load
typedef float f32x16 __attribute__((ext_vector_type(16)));

#define MFMA16(a, b, c) __builtin_amdgcn_mfma_f32_16x16x32_bf16((a), (b), (c), 0, 0, 0)
#define MFMA32(a, b, c) __builtin_amdgcn_mfma_f32_32x32x16_bf16((a), (b), (c), 0, 0, 0)
#define GLD16(g, l) __builtin_amdgcn_global_load_lds( \
    (const __attribute__((address_space(1))) void*)(g), \
    (__attribute__((address_space(3))) void*)(l), 16, 0, 0)

constexpr int Bsz = 4, SX = 2048, SC = 2048, Dm = 512, H = 8, DK = 64;
constexpr float L2E = 1.4426950408889634f;

// ---------------------------------------------------------------------------
// cvt_all: one kernel for all conversions (block-range dispatch).
// ---------------------------------------------------------------------------
__global__ __launch_bounds__(256) void cvt_all(
    const float* __restrict__ x, const float* __restrict__ c,
    const float* __restrict__ Wq, const float* __restrict__ Wk,
    const float* __restrict__ Wv, const float* __restrict__ Wo,
    const float* __restrict__ rel,
    bf16* __restrict__ xcOut, bf16* __restrict__ wOut, float* __restrict__ relT)
{
    int blk = blockIdx.x;
    if (blk < 4096) {
        int i = (blk * 256 + threadIdx.x) * 8;
        const float* src = (i < 4194304) ? x : c;
        int off = i & 4194303;
        float4 v0 = *(const float4*)(src + off);
        float4 v1 = *(const float4*)(src + off + 4);
        bf16x8 o = { (bf16)v0.x, (bf16)v0.y, (bf16)v0.z, (bf16)v0.w,
                     (bf16)v1.x, (bf16)v1.y, (bf16)v1.z, (bf16)v1.w };
        *(bf16x8*)(xcOut + i) = o;
    } else if (blk < 4608) {
        int i = ((blk - 4096) * 256 + threadIdx.x) * 8;
        int w = i >> 18;
        int off = i & 262143;
        const float* src = (w == 0) ? Wq : (w == 1) ? Wk : (w == 2) ? Wv : Wo;
        float4 v0 = *(const float4*)(src + off);
        float4 v1 = *(const float4*)(src + off + 4);
        bf16x8 o = { (bf16)v0.x, (bf16)v0.y, (bf16)v0.z, (bf16)v0.w,
                     (bf16)v1.x, (bf16)v1.y, (bf16)v1.z, (bf16)v1.w };
        *(bf16x8*)(wOut + i) = o;
    } else {
        int q = blk - 4608;
        int h = q >> 4;
        int i = (q & 15) * 256 + threadIdx.x;
        if (i < SX + SC - 1) relT[h * (SX + SC - 1) + i] = rel[i * H + h] * L2E;
    }
}

// ---------------------------------------------------------------------------
// qkv_gemm v3 = R8 single-buffer body (3 blocks/CU, proven) + LDS-staged
// COALESCED epilogue. Key fact (index algebra, all 3 layouts): this block's
// output region per head is 16 KB CONTIGUOUS in the target buffer. So stage
// the converted tile in LDS in target order (2B LDS writes), barrier, then
// each thread emits 8 fully-coalesced dwordx4 stores — replacing 64 scalar
// 2B global stores/thread (the R8 epilogue scatter).
// ---------------------------------------------------------------------------
__global__ __launch_bounds__(256, 3) void qkv_gemm(
    const bf16* __restrict__ Xbf, const bf16* __restrict__ Cbf,
    const bf16* __restrict__ Wbf,
    const float* __restrict__ bq, const float* __restrict__ bk,
    const float* __restrict__ bv,
    bf16* __restrict__ Qw, bf16* __restrict__ Kw, bf16* __restrict__ Vw)
{
    __shared__ alignas(16) bf16 smem[16384];   // As | Bs, reused as Es
    bf16* As = smem;            // 128 x 64
    bf16* Bs = smem + 8192;     // 128 x 64

    const int proj = blockIdx.x >> 2;
    const int n0 = (blockIdx.x & 3) * 128;
    const int m0 = blockIdx.y * 128;
    const bf16* A = (proj == 0) ? Xbf : Cbf;
    const bf16* W = Wbf + proj * 262144;
    const float* bias = (proj == 0) ? bq : (proj == 1) ? bk : bv;

    const int t = threadIdx.x;
    const int wid = t >> 6, lane = t & 63, lr = lane & 15, lq = lane >> 4;
    const int wm = (wid & 1) * 64, wn = (wid >> 1) * 64;

    const int rl = lane >> 3;             // 0..7 row within 8-row staging group
    const int ch = (lane & 7) ^ rl;       // xor-swizzled global 16B chunk

    f32x4 acc[4][4];
#pragma unroll
    for (int i = 0; i < 4; i++)
#pragma unroll
        for (int j = 0; j < 4; j++) acc[i][j] = f32x4{0.f, 0.f, 0.f, 0.f};

    for (int k0 = 0; k0 < Dm; k0 += 64) {
        const bf16* ga = A + (size_t)(m0 + wid * 32 + rl) * Dm + k0 + ch * 8;
        const bf16* gb = W + (size_t)(n0 + wid * 32 + rl) * Dm + k0 + ch * 8;
#pragma unroll
        for (int g = 0; g < 4; g++)
            GLD16(ga + (size_t)g * 8 * Dm, &As[(wid * 32 + g * 8) * 64]);
#pragma unroll
        for (int g = 0; g < 4; g++)
            GLD16(gb + (size_t)g * 8 * Dm, &Bs[(wid * 32 + g * 8) * 64]);
        __syncthreads();
#pragma unroll
        for (int ks = 0; ks < 2; ks++) {
            bf16x8 af[4], bfr[4];
#pragma unroll
            for (int mt = 0; mt < 4; mt++)
                af[mt] = *(const bf16x8*)&As[(wm + mt * 16 + lr) * 64 + (((ks * 4 + lq) ^ (lr & 7)) * 8)];
#pragma unroll
            for (int nt = 0; nt < 4; nt++)
                bfr[nt] = *(const bf16x8*)&Bs[(wn + nt * 16 + lr) * 64 + (((ks * 4 + lq) ^ (lr & 7)) * 8)];
#pragma unroll
            for (int mt = 0; mt < 4; mt++)
#pragma unroll
                for (int nt = 0; nt < 4; nt++)
                    acc[mt][nt] = MFMA16(af[mt], bfr[nt], acc[mt][nt]);
        }
        __syncthreads();
    }

    // ---- stage epilogue tile into LDS in TARGET layout (per head 8192 elems)
    bf16* Es = smem;   // [2][8192]
#pragma unroll
    for (int mt = 0; mt < 4; mt++) {
#pragma unroll
        for (int nt = 0; nt < 4; nt++) {
            int nl = wn + nt * 16 + lr;          // 0..127
            int head = nl >> 6, dk = nl & 63;
            float bv_ = bias[n0 + nl];
#pragma unroll
            for (int r = 0; r < 4; r++) {
                int keyl = wm + mt * 16 + lq * 4 + r;   // 0..127
                float v = acc[mt][nt][r] + bv_;
                int off;
                if (proj == 0)
                    off = keyl * 64 + dk;
                else if (proj == 1)
                    off = ((((keyl >> 5) * 4 + (dk >> 4)) * 2 + ((dk >> 3) & 1)) * 32
                           + (keyl & 31)) * 8 + (dk & 7);
                else
                    off = (((((keyl >> 6) * 4 + ((keyl >> 4) & 3)) * 2 + (dk >> 5)) * 2
                            + ((keyl >> 3) & 1)) * 32 + (dk & 31)) * 8 + (keyl & 7);
                Es[head * 8192 + off] = (bf16)v;
            }
        }
    }
    __syncthreads();

    // ---- coalesced copy-out: per head 16 KB contiguous ----
    const int b = m0 >> 11, key0 = m0 & 2047;
#pragma unroll
    for (int hh = 0; hh < 2; hh++) {
        int bh = b * 8 + (n0 >> 6) + hh;
        size_t base;
        bf16* dst;
        if (proj == 0)      { base = (size_t)(bh * 2048 + key0) * 64;        dst = Qw; }
        else if (proj == 1) { base = (size_t)(bh * 64 + (key0 >> 5)) * 2048; dst = Kw; }
        else                { base = (size_t)(bh * 32 + (key0 >> 6)) * 4096; dst = Vw; }
#pragma unroll
        for (int i = 0; i < 4; i++) {
            int e = (i * 256 + t) * 8;
            *(bf16x8*)(dst + base + e) = *(const bf16x8*)&Es[hh * 8192 + e];
        }
    }
}

// ---------------------------------------------------------------------------
// out_gemm v3: Y = A @ Wo^T + bo, fp32 out. Tile 64(M) x 128(N), BK=64,
// grid (4, 128) = 512 blocks (2/CU), single-buffer + fp32 LDS-staged epilogue
// (rows 512B-contiguous dwordx4 stores).
// ---------------------------------------------------------------------------
__global__ __launch_bounds__(256, 2) void out_gemm(
    const bf16* __restrict__ A, const bf16* __restrict__ W,
    const float* __restrict__ bias, float* __restrict__ Y)
{
    __shared__ alignas(16) char osm[32768];
    bf16* As = (bf16*)osm;              // 64 x 64 = 8 KB
    bf16* Bs = (bf16*)(osm + 8192);     // 128 x 64 = 16 KB
    float* Es = (float*)osm;            // 64 x 128 fp32 = 32 KB (after loop)

    const int t = threadIdx.x;
    const int n0 = blockIdx.x * 128;
    const int m0 = blockIdx.y * 64;
    const int wid = t >> 6, lane = t & 63, lr = lane & 15, lq = lane >> 4;
    const int wn = wid * 32;

    const int rl = lane >> 3;
    const int ch = (lane & 7) ^ rl;

    f32x4 acc[4][2];
#pragma unroll
    for (int i = 0; i < 4; i++)
#pragma unroll
        for (int j = 0; j < 2; j++) acc[i][j] = f32x4{0.f, 0.f, 0.f, 0.f};

    for (int k0 = 0; k0 < Dm; k0 += 64) {
        const bf16* ga = A + (size_t)(m0 + wid * 16 + rl) * Dm + k0 + ch * 8;
        const bf16* gb = W + (size_t)(n0 + wid * 32 + rl) * Dm + k0 + ch * 8;
#pragma unroll
        for (int g = 0; g < 2; g++)
            GLD16(ga + (size_t)g * 8 * Dm, &As[(wid * 16 + g * 8) * 64]);
#pragma unroll
        for (int g = 0; g < 4; g++)
            GLD16(gb + (size_t)g * 8 * Dm, &Bs[(wid * 32 + g * 8) * 64]);
        __syncthreads();
#pragma unroll
        for (int ks = 0; ks < 2; ks++) {
            bf16x8 af[4], bfr[2];
#pragma unroll
            for (int mt = 0; mt < 4; mt++)
                af[mt] = *(const bf16x8*)&As[(mt * 16 + lr) * 64 + (((ks * 4 + lq) ^ (lr & 7)) * 8)];
#pragma unroll
            for (int nt = 0; nt < 2; nt++)
                bfr[nt] = *(const bf16x8*)&Bs[(wn + nt * 16 + lr) * 64 + (((ks * 4 + lq) ^ (lr & 7)) * 8)];
#pragma unroll
            for (int mt = 0; mt < 4; mt++)
#pragma unroll
                for (int nt = 0; nt < 2; nt++)
                    acc[mt][nt] = MFMA16(af[mt], bfr[nt], acc[mt][nt]);
        }
        __syncthreads();
    }

    // stage fp32 tile in row-major [64][128]
#pragma unroll
    for (int mt = 0; mt < 4; mt++) {
#pragma unroll
        for (int nt = 0; nt < 2; nt++) {
            int nl = wn + nt * 16 + lr;
            float bv_ = bias[n0 + nl];
#pragma unroll
            for (int r = 0; r < 4; r++) {
                int ml = mt * 16 + lq * 4 + r;
                Es[ml * 128 + nl] = acc[mt][nt][r] + bv_;
            }
        }
    }
    __syncthreads();
    // coalesced copy-out: 512B per row segment
#pragma unroll
    for (int i = 0; i < 8; i++) {
        int e = i * 256 + t;
        int row = e >> 5, c4 = (e & 31) * 4;
        *(f32x4*)(Y + (size_t)(m0 + row) * Dm + n0 + c4) = *(const f32x4*)&Es[row * 128 + c4];
    }
}

// ---------------------------------------------------------------------------
// attn v10 = R7 exact flow (proven 70.4 µs) with the bias path changed:
// instead of staging Bsl in LDS + 128 scalar ds_read_b32 per tile, each
// (kg,r4) reads ONE float4 from relT (global, L1-resident slice, 4B-aligned
// unaligned-vec load); r0=0..3 maps to reversed lanes. Removes ~740 LDS-pipe
// cycles/tile/wave. No V-hoist (R9: in-order vmcnt made it WORSE), no unroll.
// ---------------------------------------------------------------------------
constexpr int PST = 72;  // P row stride (bf16)

__global__ __launch_bounds__(128, 4) void attn_kernel(
    const bf16* __restrict__ Qm, const bf16* __restrict__ Kf,
    const bf16* __restrict__ Vf, const float* __restrict__ relT,
    bf16* __restrict__ Oa)
{
    const int id = blockIdx.x;
    const int xcd = id & 7, j = id >> 3;
    const int bh = xcd + 8 * (j & 3);
    const int q0 = (j >> 2) * 32;
    const int h = bh & 7, b = bh >> 3;
    const int t = threadIdx.x;
    const int wid = t >> 6, lane = t & 63;
    const int l31 = lane & 31, l5 = lane >> 5;

    __shared__ alignas(16) char sm[18688];
    bf16*  Ps   = (bf16*)(sm + wid * 4608);      // per-wave 32 x PST
    float* Osum = (float*)(sm + 9216);           // 64 lanes x 36 floats
    float* Ls1  = (float*)(sm + 18432);
    float* Lfin = (float*)(sm + 18560);

    const bf16* Qb = Qm + (size_t)bh * SC * DK;
    const bf16* Kb = Kf + (size_t)bh * 64 * 2048;   // 64 key-grps x (4 ks x 512)
    const bf16* Vb = Vf + (size_t)bh * 32 * 4096;   // 32 tiles x (4 ks x 2 ng x 512)
    const float* rT = relT + h * (SX + SC - 1);

    // Q B-fragments (n=q, k=dk), resident all kernel
    bf16x8 qf[4];
#pragma unroll
    for (int ks = 0; ks < 4; ks++)
        qf[ks] = *(const bf16x8*)&Qb[(size_t)(q0 + l31) * DK + ks * 16 + l5 * 8];

    f32x16 oacc[2];
#pragma unroll
    for (int ng = 0; ng < 2; ng++)
#pragma unroll
        for (int r = 0; r < 16; r++) oacc[ng][r] = 0.f;
    float lsum = 0.f;

    const float sc = 0.125f * L2E;
    const int kw0 = wid << 10;       // wave's key base

#pragma unroll 1
    for (int tt = 0; tt < 16; ++tt) {
        const int k0 = kw0 + tt * 64;
        const int i0 = q0 - k0 + 1984;

        // ---- S^T = K·Q^T per 32-key group; exp2 with global-float4 bias ----
#pragma unroll
        for (int kg = 0; kg < 2; kg++) {
            const bf16* kb = Kb + (size_t)((k0 >> 5) + kg) * 2048 + lane * 8;
            f32x16 s;
#pragma unroll
            for (int r = 0; r < 16; r++) s[r] = 0.f;
#pragma unroll
            for (int ks = 0; ks < 4; ks++) {
                bf16x8 kf = *(const bf16x8*)(kb + ks * 512);   // contiguous 1KB wave-load
                s = MFMA32(kf, qf[ks], s);  // D[key][q], lane col = q
            }
#pragma unroll
            for (int r4 = 0; r4 < 4; r4++) {
                // bias values for r0=0..3 are rT[Cb+3-r0] : one reversed float4
                int Cb = i0 + 60 + l31 - kg * 32 - 8 * r4 - 4 * l5;
                f32x4u B4 = *(const f32x4u*)(rT + Cb);
                float p[4];
#pragma unroll
                for (int r0 = 0; r0 < 4; r0++) {
                    p[r0] = __builtin_amdgcn_exp2f(s[r4 * 4 + r0] * sc + B4[3 - r0]);
                    lsum += p[r0];
                }
                bf16x4 pk = { (bf16)p[0], (bf16)p[1], (bf16)p[2], (bf16)p[3] };
                *(bf16x4*)&Ps[l31 * PST + kg * 32 + 8 * r4 + 4 * l5] = pk;
            }
        }
        // ---- O += P @ V  (same-wave LDS RAW; no barrier) ----
        bf16x8 pf[4];
#pragma unroll
        for (int ks = 0; ks < 4; ks++)
            pf[ks] = *(const bf16x8*)&Ps[l31 * PST + ks * 16 + l5 * 8];
        const bf16* vb = Vb + (size_t)(k0 >> 6) * 4096 + lane * 8;
#pragma unroll
        for (int ng = 0; ng < 2; ng++) {
#pragma unroll
            for (int ks = 0; ks < 4; ks++) {
                bf16x8 vf = *(const bf16x8*)(vb + ng * 512 + ks * 1024);  // contiguous 1KB
                oacc[ng] = MFMA32(pf[ks], vf, oacc[ng]);  // D[q][dk], lane col = dk
            }
        }
    }

    // ---- 2-way combine ----
    lsum += __shfl_xor(lsum, 32, 64);
    if (wid == 1) {
        if (lane < 32) Ls1[l31] = lsum;
        float* Op = Osum + lane * 36;
#pragma unroll
        for (int ng = 0; ng < 2; ng++)
#pragma unroll
            for (int q = 0; q < 4; q++) {
                f32x4 v = { oacc[ng][q * 4 + 0], oacc[ng][q * 4 + 1],
                            oacc[ng][q * 4 + 2], oacc[ng][q * 4 + 3] };
                *(f32x4*)(Op + ng * 16 + q * 4) = v;
            }
    }
    __syncthreads();
    if (wid == 0) {
        lsum += Ls1[l31];
        const float* Op = Osum + lane * 36;
#pragma unroll
        for (int ng = 0; ng < 2; ng++)
#pragma unroll
            for (int q = 0; q < 4; q++) {
                f32x4 v = *(const f32x4*)(Op + ng * 16 + q * 4);
#pragma unroll
                for (int r0 = 0; r0 < 4; r0++) oacc[ng][q * 4 + r0] += v[r0];
            }
        if (lane < 32) Lfin[l31] = lsum;
        // epilogue: normalize, store bf16 [b][q][h*64+dk]
#pragma unroll
        for (int r4 = 0; r4 < 4; r4++) {
            float4 lv = *(const float4*)&Lfin[8 * r4 + 4 * l5];
            float rv[4] = { 1.f / lv.x, 1.f / lv.y, 1.f / lv.z, 1.f / lv.w };
#pragma unroll
            for (int ng = 0; ng < 2; ng++) {
#pragma unroll
                for (int r0 = 0; r0 < 4; r0++) {
                    int row = r0 + 8 * r4 + 4 * l5;
                    Oa[((size_t)(b * SX + q0 + row)) * Dm + h * 64 + ng * 32 + l31] =
                        (bf16)(oacc[ng][r4 * 4 + r0] * rv[r0]);
                }
            }
        }
    }
}

// ---------------------------------------------------------------------------
// Launch
// ---------------------------------------------------------------------------
extern "C" void kernel_launch(void* const* d_in, const int* in_sizes, int n_in,
                              void* d_out, int out_size, void* d_ws, size_t ws_size,
                              hipStream_t stream)
{
    (void)in_sizes; (void)n_in; (void)out_size; (void)ws_size;

    const float* x   = (const float*)d_in[0];
    const float* c   = (const float*)d_in[1];
    const float* Wq  = (const float*)d_in[2];
    const float* bq  = (const float*)d_in[3];
    const float* Wk  = (const float*)d_in[4];
    const float* bk  = (const float*)d_in[5];
    const float* Wv  = (const float*)d_in[6];
    const float* bv  = (const float*)d_in[7];
    const float* Wo  = (const float*)d_in[8];
    const float* bo  = (const float*)d_in[9];
    const float* rel = (const float*)d_in[10];

    char* ws = (char*)d_ws;
    // layout: Wbf 0..2MB | XCbf 2..18MB (dead after QKV) / Aw overlay 2..10MB
    //         Q 18..26 | Kf 26..34 | Vf 34..42 | relT 42MB+128KB
    bf16*  Wbf  = (bf16*)ws;
    bf16*  Xbf  = (bf16*)(ws + (2u << 20));
    bf16*  Cbf  = Xbf + 4194304;
    bf16*  Aw   = (bf16*)(ws + (2u << 20));      // overlays XCbf (dead by then)
    bf16*  Qw   = (bf16*)(ws + (18u << 20));
    bf16*  Kw   = (bf16*)(ws + (26u << 20));
    bf16*  Vw   = (bf16*)(ws + (34u << 20));
    float* relT = (float*)(ws + (42u << 20));

    cvt_all<<<4736, 256, 0, stream>>>(x, c, Wq, Wk, Wv, Wo, rel, Xbf, Wbf, relT);

    qkv_gemm<<<dim3(12, 64), 256, 0, stream>>>(Xbf, Cbf, Wbf, bq, bk, bv, Qw, Kw, Vw);

    attn_kernel<<<2048, 128, 0, stream>>>(Qw, Kw, Vw, relT, Aw);

    out_gemm<<<dim3(4, 128), 256, 0, stream>>>(Aw, Wbf + 3 * 262144, bo, (float*)d_out);
}